// Round 6
// baseline (398.553 us; speedup 1.0000x reference)
//
#include <hip/hip_runtime.h>

// LightGCN on MI355X, round 24.
// r18: sequential-write build -> 392.7 (spmm 3x60us). r19/r20: spmm MLP 2->8
//      = zero effect. r22: CHUNK 8192 exposed scalar pass_a (73us, VGPR=8).
// r23: pass_a 4-wide vectorized + CHUNK 4096 -> 385.4 (best). spmm nt hints:
//      FETCH 159->154MB but dur 60->62 = net loss. spmm diagnosis closed:
//      per-CU outstanding-miss ceiling (~10.7 B/cy/CU; BW models say 10-25us,
//      VALU@100% 31us, measured 60us, MLP-invariant) -> ~60us structural
//      floor for gather-CSR spmm; stop spending rounds there.
// r24: (1) spmm reverted to exact r18 loop (drop nt: -2us x3).
//      (2) conv_bf16 fused into pass_a dispatch as tail blocks - pass_a is
//      latency-bound (VALU 4%, HBM 10%), conv's ~7us of streaming hides in
//      its bubbles. Needs xb0 off the tmp_ii overlay -> fresh region at
//      +71.56MB, guarded by ws_size >= 84.4MB (else exact r23 fallback).
// Predict: spmm ~60.0/159MB, pass_a +0-2us, total ~370-375.

#define MM 100000
#define UU 50000
#define DD 64
#define RPB 128           // rows per bucket
#define BSH 7
#define NBMAX 800
#define CHUNK 4096
#define STAGE_B 4608      // pass_b stage entries (= CAPE_II)
#define CAPE_II 4608      // edges stride II
#define CAPE_UI 1024      // edges stride UI

__device__ __forceinline__ unsigned short f2bf(float f) {
    unsigned int b = __float_as_uint(f);
    b += 0x7FFF + ((b >> 16) & 1);          // round-to-nearest-even
    return (unsigned short)(b >> 16);
}
// packed edge: (dst << 15) | (bf16(val) & 0x7FFF); val >= 0 so sign bit unused
__device__ __forceinline__ float pk_val(unsigned int w) {
    return __uint_as_float((w & 0x7FFFu) << 16);
}
__device__ __forceinline__ int pk_dst(unsigned int w) { return (int)(w >> 15); }

// ---- pass A (+ optional fused conv tail blocks) ----
// binning blocks: LDS bin + block-contiguous sequential flush + offset table.
// conv blocks (blockIdx >= nchunks_ii+nchunks_ui): fp32->bf16 table convert,
// hides under pass_a's latency bubbles (pass_a: VALU 4%, HBM 10%).
__global__ void pass_a(const int* __restrict__ src_ii, const int* __restrict__ dst_ii,
                       const float* __restrict__ val_ii, int2* __restrict__ tmp_ii,
                       int* __restrict__ tab_ii, int nnz_ii, int nb_ii, int nchunks_ii,
                       const int* __restrict__ src_ui, const int* __restrict__ dst_ui,
                       const float* __restrict__ val_ui, int2* __restrict__ tmp_ui,
                       int* __restrict__ tab_ui, int nnz_ui, int nb_ui, int nchunks_ui,
                       const unsigned char* __restrict__ filter,
                       const float4* __restrict__ conv_in, ushort4* __restrict__ conv_out,
                       int n4) {
    extern __shared__ char smem[];
    const int nbin_blocks = nchunks_ii + nchunks_ui;
    int cb = (int)blockIdx.x - nbin_blocks;
    if (cb >= 0) {                               // ---- fused conv tail ----
        int i = cb * 1024 + (int)threadIdx.x;
        if (i < n4) {
            float4 v = conv_in[i];
            conv_out[i] = make_ushort4(f2bf(v.x), f2bf(v.y), f2bf(v.z), f2bf(v.w));
        }
        i += 512;
        if (i < n4) {
            float4 v = conv_in[i];
            conv_out[i] = make_ushort4(f2bf(v.x), f2bf(v.y), f2bf(v.z), f2bf(v.w));
        }
        return;
    }
    int2* stage = (int2*)smem;                     // CHUNK entries (32 KB)
    int*  lcnt  = (int*)(smem + CHUNK * 8);        // NBMAX
    int*  lbase = lcnt + NBMAX;                    // NBMAX+1
    int*  lcur  = lbase + NBMAX + 1;               // NBMAX
    const bool is_ii = (blockIdx.x < (unsigned)nchunks_ii);
    const int chunk_id = is_ii ? blockIdx.x : (blockIdx.x - nchunks_ii);
    const int* __restrict__ src = is_ii ? src_ii : src_ui;
    const int* __restrict__ dst = is_ii ? dst_ii : dst_ui;
    const float* __restrict__ val = is_ii ? val_ii : val_ui;
    int2* __restrict__ tmp = is_ii ? tmp_ii : tmp_ui;
    int*  __restrict__ tab = is_ii ? tab_ii : tab_ui;
    const int nnz = is_ii ? nnz_ii : nnz_ui;
    const int nb  = is_ii ? nb_ii : nb_ui;
    const unsigned char* __restrict__ flt = is_ii ? nullptr : filter;

    int t = threadIdx.x;
    for (int i = t; i < nb; i += blockDim.x) lcnt[i] = 0;
    __syncthreads();
    int beg = chunk_id * CHUNK, end = min(nnz, beg + CHUNK);
    // ---- count pass: 4-wide vector loads (16B aligned: beg is CHUNK-mult) ----
    for (int i = beg + 4 * t; i < end; i += 4 * blockDim.x) {
        if (i + 3 < end) {
            const int4 s4 = *(const int4*)(src + i);
            if (!flt) {
                atomicAdd(&lcnt[s4.x >> BSH], 1);
                atomicAdd(&lcnt[s4.y >> BSH], 1);
                atomicAdd(&lcnt[s4.z >> BSH], 1);
                atomicAdd(&lcnt[s4.w >> BSH], 1);
            } else {
                if (flt[s4.x]) atomicAdd(&lcnt[s4.x >> BSH], 1);
                if (flt[s4.y]) atomicAdd(&lcnt[s4.y >> BSH], 1);
                if (flt[s4.z]) atomicAdd(&lcnt[s4.z >> BSH], 1);
                if (flt[s4.w]) atomicAdd(&lcnt[s4.w >> BSH], 1);
            }
        } else {
            for (int k = i; k < end; k++) {
                int s = src[k];
                if (flt && !flt[s]) continue;
                atomicAdd(&lcnt[s >> BSH], 1);
            }
        }
    }
    __syncthreads();
    // wave 0: exclusive scan lcnt -> lbase[0..nb], lbase[nb] = total
    if (t < 64) {
        int carry = 0;
        for (int g = 0; g < nb; g += 64) {
            int i = g + t;
            int v = (i < nb) ? lcnt[i] : 0;
            int incl = v;
            #pragma unroll
            for (int m = 1; m < 64; m <<= 1) {
                int u = __shfl_up(incl, m, 64);
                if (t >= m) incl += u;
            }
            if (i < nb) lbase[i] = carry + incl - v;
            carry += __shfl(incl, 63, 64);
        }
        if (t == 0) lbase[nb] = carry;
    }
    __syncthreads();
    for (int i = t; i < nb; i += blockDim.x) lcur[i] = lbase[i];
    __syncthreads();
    // ---- bin pass: 4-wide (src,dst,val all in flight -> MLP 3) ----
    for (int i = beg + 4 * t; i < end; i += 4 * blockDim.x) {
        if (i + 3 < end) {
            const int4   s4 = *(const int4*)(src + i);
            const int4   d4 = *(const int4*)(dst + i);
            const float4 v4 = *(const float4*)(val + i);
            if (!flt || flt[s4.x]) {
                int pos = atomicAdd(&lcur[s4.x >> BSH], 1);
                stage[pos] = make_int2(d4.x | ((s4.x & (RPB - 1)) << 17), __float_as_int(v4.x));
            }
            if (!flt || flt[s4.y]) {
                int pos = atomicAdd(&lcur[s4.y >> BSH], 1);
                stage[pos] = make_int2(d4.y | ((s4.y & (RPB - 1)) << 17), __float_as_int(v4.y));
            }
            if (!flt || flt[s4.z]) {
                int pos = atomicAdd(&lcur[s4.z >> BSH], 1);
                stage[pos] = make_int2(d4.z | ((s4.z & (RPB - 1)) << 17), __float_as_int(v4.z));
            }
            if (!flt || flt[s4.w]) {
                int pos = atomicAdd(&lcur[s4.w >> BSH], 1);
                stage[pos] = make_int2(d4.w | ((s4.w & (RPB - 1)) << 17), __float_as_int(v4.w));
            }
        } else {
            for (int k = i; k < end; k++) {
                int s = src[k];
                if (flt && !flt[s]) continue;
                int pos = atomicAdd(&lcur[s >> BSH], 1);
                stage[pos] = make_int2(dst[k] | ((s & (RPB - 1)) << 17), __float_as_int(val[k]));
            }
        }
    }
    __syncthreads();
    // SEQUENTIAL flush (int4-wide): block-contiguous region + table row.
    // May copy one garbage int2 past total (stays within CHUNK, never read).
    int total = lbase[nb];
    int4* outp4 = (int4*)(tmp + (size_t)chunk_id * CHUNK);
    const int4* st4 = (const int4*)stage;
    int tot4 = (total + 1) >> 1;
    for (int i = t; i < tot4; i += blockDim.x) outp4[i] = st4[i];
    int* trow = tab + (size_t)chunk_id * (nb + 1);
    for (int i = t; i <= nb; i += blockDim.x) trow[i] = lbase[i];
}

// ---- pass B: block = bucket; gather segments via table, LDS sort, sequential write ----
__global__ void pass_b(const int2* __restrict__ tmp_ii, const int* __restrict__ tab_ii,
                       int nch_ii, unsigned int* __restrict__ edges_ii,
                       int* __restrict__ rp_ii, int* __restrict__ rpe_ii, int nb_ii,
                       const int2* __restrict__ tmp_ui, const int* __restrict__ tab_ui,
                       int nch_ui, unsigned int* __restrict__ edges_ui,
                       int* __restrict__ rp_ui, int* __restrict__ rpe_ui) {
    __shared__ int2 stage[STAGE_B];            // 36,864 B
    __shared__ unsigned int outs[STAGE_B];     // 18,432 B
    __shared__ int tsum[512];
    __shared__ int cnt[RPB];
    __shared__ int cur[RPB];
    __shared__ int sc[RPB];
    const bool is_ii = (blockIdx.x < (unsigned)nb_ii);
    const int b = is_ii ? blockIdx.x : (blockIdx.x - nb_ii);
    const int2* __restrict__ tmp = is_ii ? tmp_ii : tmp_ui;
    const int* __restrict__ tab = is_ii ? tab_ii : tab_ui;
    unsigned int* __restrict__ edges = is_ii ? edges_ii : edges_ui;
    int* __restrict__ rp  = is_ii ? rp_ii : rp_ui;
    int* __restrict__ rpe = is_ii ? rpe_ii : rpe_ui;
    const int nch = is_ii ? nch_ii : nch_ui;
    const int nbp1 = (is_ii ? nb_ii : (gridDim.x - nb_ii)) + 1;
    const int n_rows = is_ii ? MM : UU;
    const int cap_e = is_ii ? CAPE_II : CAPE_UI;

    int t = threadIdx.x;
    // phase 0: per-thread segment-length sums over assigned chunks
    int mysum = 0;
    for (int c = t; c < nch; c += 512)
        mysum += tab[(size_t)c * nbp1 + b + 1] - tab[(size_t)c * nbp1 + b];
    tsum[t] = mysum;
    __syncthreads();
    for (int off = 1; off < 512; off <<= 1) {
        int u = (t >= off) ? tsum[t - off] : 0;
        __syncthreads();
        tsum[t] += u;
        __syncthreads();
    }
    int mybase = tsum[t] - mysum;
    int total = tsum[511];
    // phase 1: gather segments into LDS stage (random ~84B reads, high MLP)
    for (int c = t; c < nch; c += 512) {
        int s0 = tab[(size_t)c * nbp1 + b];
        int s1 = tab[(size_t)c * nbp1 + b + 1];
        const int2* seg = tmp + (size_t)c * CHUNK + s0;
        for (int k = 0; k < s1 - s0; k++) stage[mybase++] = seg[k];
    }
    __syncthreads();
    // phase 2: row hist -> scan -> rp/rpe -> scatter to LDS out -> sequential store
    if (t < RPB) cnt[t] = 0;
    __syncthreads();
    for (int i = t; i < total; i += 512)
        atomicAdd(&cnt[(stage[i].x >> 17) & (RPB - 1)], 1);
    __syncthreads();
    int v = 0;
    if (t < RPB) { v = cnt[t]; sc[t] = v; }
    __syncthreads();
    for (int off = 1; off < RPB; off <<= 1) {
        int u = 0;
        if (t < RPB && t >= off) u = sc[t - off];
        __syncthreads();
        if (t < RPB) sc[t] += u;
        __syncthreads();
    }
    int ebeg = b * cap_e;
    if (t < RPB) {
        int excl = sc[t] - v;
        int r = (b << BSH) + t;
        if (r < n_rows) { rp[r] = ebeg + excl; rpe[r] = ebeg + excl + v; }
        cur[t] = excl;
    }
    __syncthreads();
    for (int i = t; i < total; i += 512) {
        int2 e = stage[i];
        int s = (e.x >> 17) & (RPB - 1);
        int pos = atomicAdd(&cur[s], 1);
        outs[pos] = ((unsigned int)(e.x & 0x1FFFF) << 15) | (f2bf(__int_as_float(e.y)) & 0x7FFFu);
    }
    __syncthreads();
    unsigned int* eg = edges + (size_t)ebeg;
    for (int i = t; i < total; i += 512) eg[i] = outs[i];
}

// ---- fp32 -> bf16 table conversion (fallback when conv not fused) ----
__global__ void conv_bf16(const float4* __restrict__ in, ushort4* __restrict__ out, int n4) {
    int i = blockIdx.x * blockDim.x + threadIdx.x;
    if (i >= n4) return;
    float4 v = in[i];
    ushort4 o;
    o.x = f2bf(v.x); o.y = f2bf(v.y); o.z = f2bf(v.z); o.w = f2bf(v.w);
    out[i] = o;
}

// ---- propagation SpMM: r18 dual-row quad-edge gather, bf16 acc (frozen) ----
template <bool WRITE_Y, bool INIT_ACC>
__global__ void spmm_bf16(const int* __restrict__ rp, const int* __restrict__ rpe,
                          const unsigned int* __restrict__ edges,
                          const unsigned short* __restrict__ xb, unsigned short* __restrict__ yb,
                          const unsigned short* __restrict__ e0b, unsigned short* __restrict__ accb,
                          const float* __restrict__ att, int layer, int n_rows) {
    int wid = (blockIdx.x * blockDim.x + threadIdx.x) >> 6;
    int lane = threadIdx.x & 63;
    int r0 = wid * 2;
    if (r0 >= n_rows) return;
    int r1 = r0 + 1;
    bool has1 = (r1 < n_rows);
    int q = lane >> 4, sub = lane & 15;
    int eA = rp[r0], endA = rpe[r0];
    int eB = has1 ? rp[r1] : 0, endB = has1 ? rpe[r1] : 0;
    float a0 = 0.f, a1 = 0.f, a2 = 0.f, a3 = 0.f;
    float b0 = 0.f, b1 = 0.f, b2 = 0.f, b3 = 0.f;
    while (eA < endA || eB < endB) {
        unsigned int evA = 0u, evB = 0u;
        int stepsA = 0, stepsB = 0;
        if (eA < endA) {
            int idx = eA + lane;
            evA = (idx < endA) ? edges[idx] : 0u;
            stepsA = (min(64, endA - eA) + 3) >> 2;
        }
        if (eB < endB) {
            int idx = eB + lane;
            evB = (idx < endB) ? edges[idx] : 0u;
            stepsB = (min(64, endB - eB) + 3) >> 2;
        }
        int steps = max(stepsA, stepsB);
        int jq = q;
        for (int st = 0; st < steps; ++st, jq += 4) {
            unsigned int pA = (st < stepsA) ? (unsigned)__shfl((int)evA, jq, 64) : 0u;
            unsigned int pB = (st < stepsB) ? (unsigned)__shfl((int)evB, jq, 64) : 0u;
            const uint2 uA = *((const uint2*)(xb + ((size_t)pk_dst(pA) << 6)) + sub);
            const uint2 uB = *((const uint2*)(xb + ((size_t)pk_dst(pB) << 6)) + sub);
            float vA = pk_val(pA);
            float vB = pk_val(pB);
            a0 = fmaf(vA, __uint_as_float(uA.x << 16), a0);
            a1 = fmaf(vA, __uint_as_float(uA.x & 0xFFFF0000u), a1);
            a2 = fmaf(vA, __uint_as_float(uA.y << 16), a2);
            a3 = fmaf(vA, __uint_as_float(uA.y & 0xFFFF0000u), a3);
            b0 = fmaf(vB, __uint_as_float(uB.x << 16), b0);
            b1 = fmaf(vB, __uint_as_float(uB.x & 0xFFFF0000u), b1);
            b2 = fmaf(vB, __uint_as_float(uB.y << 16), b2);
            b3 = fmaf(vB, __uint_as_float(uB.y & 0xFFFF0000u), b3);
        }
        eA += 64; eB += 64;
    }
    a0 += __shfl_xor(a0, 16, 64); a0 += __shfl_xor(a0, 32, 64);
    a1 += __shfl_xor(a1, 16, 64); a1 += __shfl_xor(a1, 32, 64);
    a2 += __shfl_xor(a2, 16, 64); a2 += __shfl_xor(a2, 32, 64);
    a3 += __shfl_xor(a3, 16, 64); a3 += __shfl_xor(a3, 32, 64);
    b0 += __shfl_xor(b0, 16, 64); b0 += __shfl_xor(b0, 32, 64);
    b1 += __shfl_xor(b1, 16, 64); b1 += __shfl_xor(b1, 32, 64);
    b2 += __shfl_xor(b2, 16, 64); b2 += __shfl_xor(b2, 32, 64);
    b3 += __shfl_xor(b3, 16, 64); b3 += __shfl_xor(b3, 32, 64);
    if (lane < 32 && (lane < 16 || has1)) {
        float s0 = (lane < 16) ? a0 : b0;
        float s1 = (lane < 16) ? a1 : b1;
        float s2 = (lane < 16) ? a2 : b2;
        float s3 = (lane < 16) ? a3 : b3;
        int r = (lane < 16) ? r0 : r1;
        float a = att[layer];
        s0 *= a; s1 *= a; s2 *= a; s3 *= a;
        size_t o = (size_t)r * DD + 4 * sub;
        if (WRITE_Y) {
            ushort4 yv = make_ushort4(f2bf(s0), f2bf(s1), f2bf(s2), f2bf(s3));
            *(ushort4*)(yb + o) = yv;
        }
        const uint2 u0 = *(const uint2*)((INIT_ACC ? e0b : accb) + o);
        s0 += __uint_as_float(u0.x << 16);
        s1 += __uint_as_float(u0.x & 0xFFFF0000u);
        s2 += __uint_as_float(u0.y << 16);
        s3 += __uint_as_float(u0.y & 0xFFFF0000u);
        *(ushort4*)(accb + o) = make_ushort4(f2bf(s0), f2bf(s1), f2bf(s2), f2bf(s3));
    }
}

__global__ void set_bitmap(const int* __restrict__ users, unsigned char* __restrict__ bm, int B) {
    int i = blockIdx.x * blockDim.x + threadIdx.x;
    if (i < B) bm[users[i]] = 1;
}

// fused UI-SpMM + pair dot: quad-edge gather over bf16 acc table (frozen)
__global__ void user_dot_kernel(const int* __restrict__ users, const int* __restrict__ items,
                                const int* __restrict__ rp, const int* __restrict__ rpe,
                                const unsigned int* __restrict__ edges,
                                const unsigned short* __restrict__ accb,
                                float* __restrict__ out, int B) {
    int w = (blockIdx.x * blockDim.x + threadIdx.x) >> 6;
    int lane = threadIdx.x & 63;
    if (w >= B) return;
    int q = lane >> 4, sub = lane & 15;
    int u = users[w];
    int beg = rp[u], end = rpe[u];
    float s0 = 0.f, s1 = 0.f, s2 = 0.f, s3 = 0.f;
    for (int e = beg; e < end; e += 64) {
        int idx = e + lane;
        unsigned int ev = (idx < end) ? edges[idx] : 0u;
        int cnt = min(64, end - e);
        int steps = (cnt + 3) >> 2;
        int jq = q;
        for (int st = 0; st < steps; ++st, jq += 4) {
            unsigned int p = (unsigned)__shfl((int)ev, jq, 64);
            float v = pk_val(p);
            const uint2 x = *((const uint2*)(accb + ((size_t)pk_dst(p) << 6)) + sub);
            s0 = fmaf(v, __uint_as_float(x.x << 16), s0);
            s1 = fmaf(v, __uint_as_float(x.x & 0xFFFF0000u), s1);
            s2 = fmaf(v, __uint_as_float(x.y << 16), s2);
            s3 = fmaf(v, __uint_as_float(x.y & 0xFFFF0000u), s3);
        }
    }
    s0 += __shfl_xor(s0, 16, 64); s0 += __shfl_xor(s0, 32, 64);
    s1 += __shfl_xor(s1, 16, 64); s1 += __shfl_xor(s1, 32, 64);
    s2 += __shfl_xor(s2, 16, 64); s2 += __shfl_xor(s2, 32, 64);
    s3 += __shfl_xor(s3, 16, 64); s3 += __shfl_xor(s3, 32, 64);
    float p = 0.f;
    if (lane < 16) {
        const uint2 iu = *((const uint2*)(accb + ((size_t)items[w] << 6)) + sub);
        p = s0 * __uint_as_float(iu.x << 16)
          + s1 * __uint_as_float(iu.x & 0xFFFF0000u)
          + s2 * __uint_as_float(iu.y << 16)
          + s3 * __uint_as_float(iu.y & 0xFFFF0000u);
        #pragma unroll
        for (int m = 8; m >= 1; m >>= 1) p += __shfl_xor(p, m, 64);
        if (sub == 0) out[w] = p * 0.0625f;   // (1/4 mean) each side
    }
}

extern "C" void kernel_launch(void* const* d_in, const int* in_sizes, int n_in,
                              void* d_out, int out_size, void* d_ws, size_t ws_size,
                              hipStream_t stream) {
    const int*   users    = (const int*)d_in[0];
    const int*   items    = (const int*)d_in[1];
    const int*   ii_src   = (const int*)d_in[2];
    const int*   ii_dst   = (const int*)d_in[3];
    const float* ii_val   = (const float*)d_in[4];
    const int*   ui_src   = (const int*)d_in[5];
    const int*   ui_dst   = (const int*)d_in[6];
    const float* ui_val   = (const float*)d_in[7];
    const float* item_emb = (const float*)d_in[8];
    const float* att      = (const float*)d_in[9];

    const int E_ii = in_sizes[2];
    const int E_ui = in_sizes[5];
    const int B    = in_sizes[0];
    const int NB_ii = (MM + RPB - 1) / RPB;              // 782
    const int NB_ui = (UU + RPB - 1) / RPB;              // 391
    const int nchunks_ii = (E_ii + CHUNK - 1) / CHUNK;   // 782
    const int nchunks_ui = (E_ui + CHUNK - 1) / CHUNK;   // 391

    char* w = (char*)d_ws;
    // tmp_ii 782*4096*8 = 25,624,576; after pass_b overlaid by y1 (and xb0 in
    // fallback mode)
    int2*  tmp_ii = (int2*)(w);
    unsigned short* xb0_old = (unsigned short*)(w);               // 12.8 MB (fallback)
    unsigned short* y1  = (unsigned short*)(w + 12800000);        // 12.8 MB
    // tmp_ui 391*4096*8 = 12,812,288 @25,624,576; overlaid by y2 (12.8 MB)
    int2*  tmp_ui = (int2*)(w + 25624576);
    unsigned short* y2  = (unsigned short*)(w + 25624576);
    unsigned short* accb = (unsigned short*)(w + 38436864);       // 12.8 MB bf16
    unsigned int* edges_ii = (unsigned int*)(w + 51236864);       // 782*4608*4 = 14,413,824
    unsigned int* edges_ui = (unsigned int*)(w + 65650688);       // 391*1024*4 = 1,601,536
    int*   tab_ii = (int*)(w + 67252224);                         // 782*783*4 = 2,449,224
    int*   tab_ui = (int*)(w + 69701448);                         // 391*392*4 = 613,088
    int*   rp_ii  = (int*)(w + 70314536);                         // (MM+2)*4
    int*   rpe_ii = (int*)(w + 70714544);
    int*   rp_ui  = (int*)(w + 71114552);                         // (UU+2)*4
    int*   rpe_ui = (int*)(w + 71314560);
    unsigned char* bitmap = (unsigned char*)(w + 71514568);       // UU bytes
    // fused-conv mode: xb0 in fresh region (no tmp_ii overlay) so conv can run
    // concurrently with pass_a binning blocks
    unsigned short* xb0_new = (unsigned short*)(w + 71564576);    // 12.8 MB
    const size_t ws_need_fused = 71564576 + 12800000;             // 84,364,576
    const bool fuse_conv = (ws_size >= ws_need_fused);
    unsigned short* xb0 = fuse_conv ? xb0_new : xb0_old;

    const int TB = 256;
    const int TBB = 512;
    const size_t smem_a = CHUNK * 8 + (3 * NBMAX + 8) * 4;   // ~42.4 KB -> 3 blocks/CU
    const int n4 = MM * DD / 4;                              // 1,600,000 float4s
    const int nconv = fuse_conv ? (n4 + 1023) / 1024 : 0;    // 1563 tail blocks

    // ---- bitmap memset + set ----
    hipMemsetAsync(bitmap, 0, UU, stream);
    set_bitmap<<<(B + TB - 1) / TB, TB, 0, stream>>>(users, bitmap, B);

    // ---- both graphs: binning (sequential flush) + optional fused conv ----
    pass_a<<<nchunks_ii + nchunks_ui + nconv, TBB, smem_a, stream>>>(
        ii_src, ii_dst, ii_val, tmp_ii, tab_ii, E_ii, NB_ii, nchunks_ii,
        ui_src, ui_dst, ui_val, tmp_ui, tab_ui, E_ui, NB_ui, nchunks_ui, bitmap,
        (const float4*)item_emb, (ushort4*)xb0, n4);
    pass_b<<<NB_ii + NB_ui, TBB, 0, stream>>>(
        tmp_ii, tab_ii, nchunks_ii, edges_ii, rp_ii, rpe_ii, NB_ii,
        tmp_ui, tab_ui, nchunks_ui, edges_ui, rp_ui, rpe_ui);

    // ---- bf16 x0 fallback conversion (only when not fused), 3 layers ----
    if (!fuse_conv)
        conv_bf16<<<(n4 + TB - 1) / TB, TB, 0, stream>>>((const float4*)item_emb, (ushort4*)xb0, n4);
    const int nwaves = (MM + 1) / 2;                      // dual-row waves
    const int ii_blocks = (nwaves * 64 + TB - 1) / TB;
    spmm_bf16<true,  true ><<<ii_blocks, TB, 0, stream>>>(rp_ii, rpe_ii, edges_ii, xb0, y1, xb0, accb, att, 0, MM);
    spmm_bf16<true,  false><<<ii_blocks, TB, 0, stream>>>(rp_ii, rpe_ii, edges_ii, y1,  y2, nullptr, accb, att, 1, MM);
    spmm_bf16<false, false><<<ii_blocks, TB, 0, stream>>>(rp_ii, rpe_ii, edges_ii, y2,  nullptr, nullptr, accb, att, 2, MM);

    // ---- fused user aggregation + pair dot ----
    user_dot_kernel<<<(B * 64 + TB - 1) / TB, TB, 0, stream>>>(users, items, rp_ui, rpe_ui, edges_ui, accb,
                                                               (float*)d_out, B);
}

// Round 7
// 368.995 us; speedup vs baseline: 1.0801x; 1.0801x over previous
//
#include <hip/hip_runtime.h>

// LightGCN on MI355X, round 25.
// r23: pass_a 4-wide vectorized -> 385.4 (best). spmm diagnosed closed:
//      beyond-L2 transaction-rate ceiling, ~60us structural floor.
// r24: conv fused into pass_a (+fresh xb0 region) -> 398.6 FAILED on a bug:
//      xb0_new offset 71,564,576 = 32 mod 128 -> every 128B row gather
//      straddled 2 cache lines -> layer-0 spmm FETCH 154->293MB, dur 60->87.7.
//      But total only +13.2 => the fusion itself SAVED ~14us on the build.
//      (Also: 2x line traffic -> only 1.46x time = adjacent-line pairs are
//      cheaper than random singles; confirms transaction-rate model.)
// r25: xb0_new moved to 4096-aligned offset 71,565,312. Everything else
//      identical to r24. Predict: L0 spmm back to ~60us / ~158MB, total ~370.

#define MM 100000
#define UU 50000
#define DD 64
#define RPB 128           // rows per bucket
#define BSH 7
#define NBMAX 800
#define CHUNK 4096
#define STAGE_B 4608      // pass_b stage entries (= CAPE_II)
#define CAPE_II 4608      // edges stride II
#define CAPE_UI 1024      // edges stride UI

__device__ __forceinline__ unsigned short f2bf(float f) {
    unsigned int b = __float_as_uint(f);
    b += 0x7FFF + ((b >> 16) & 1);          // round-to-nearest-even
    return (unsigned short)(b >> 16);
}
// packed edge: (dst << 15) | (bf16(val) & 0x7FFF); val >= 0 so sign bit unused
__device__ __forceinline__ float pk_val(unsigned int w) {
    return __uint_as_float((w & 0x7FFFu) << 16);
}
__device__ __forceinline__ int pk_dst(unsigned int w) { return (int)(w >> 15); }

// ---- pass A (+ fused conv tail blocks) ----
// binning blocks: LDS bin + block-contiguous sequential flush + offset table.
// conv blocks (blockIdx >= nchunks_ii+nchunks_ui): fp32->bf16 table convert,
// hides under pass_a's latency bubbles (pass_a: VALU 4%, HBM 10%).
__global__ void pass_a(const int* __restrict__ src_ii, const int* __restrict__ dst_ii,
                       const float* __restrict__ val_ii, int2* __restrict__ tmp_ii,
                       int* __restrict__ tab_ii, int nnz_ii, int nb_ii, int nchunks_ii,
                       const int* __restrict__ src_ui, const int* __restrict__ dst_ui,
                       const float* __restrict__ val_ui, int2* __restrict__ tmp_ui,
                       int* __restrict__ tab_ui, int nnz_ui, int nb_ui, int nchunks_ui,
                       const unsigned char* __restrict__ filter,
                       const float4* __restrict__ conv_in, ushort4* __restrict__ conv_out,
                       int n4) {
    extern __shared__ char smem[];
    const int nbin_blocks = nchunks_ii + nchunks_ui;
    int cb = (int)blockIdx.x - nbin_blocks;
    if (cb >= 0) {                               // ---- fused conv tail ----
        int i = cb * 1024 + (int)threadIdx.x;
        if (i < n4) {
            float4 v = conv_in[i];
            conv_out[i] = make_ushort4(f2bf(v.x), f2bf(v.y), f2bf(v.z), f2bf(v.w));
        }
        i += 512;
        if (i < n4) {
            float4 v = conv_in[i];
            conv_out[i] = make_ushort4(f2bf(v.x), f2bf(v.y), f2bf(v.z), f2bf(v.w));
        }
        return;
    }
    int2* stage = (int2*)smem;                     // CHUNK entries (32 KB)
    int*  lcnt  = (int*)(smem + CHUNK * 8);        // NBMAX
    int*  lbase = lcnt + NBMAX;                    // NBMAX+1
    int*  lcur  = lbase + NBMAX + 1;               // NBMAX
    const bool is_ii = (blockIdx.x < (unsigned)nchunks_ii);
    const int chunk_id = is_ii ? blockIdx.x : (blockIdx.x - nchunks_ii);
    const int* __restrict__ src = is_ii ? src_ii : src_ui;
    const int* __restrict__ dst = is_ii ? dst_ii : dst_ui;
    const float* __restrict__ val = is_ii ? val_ii : val_ui;
    int2* __restrict__ tmp = is_ii ? tmp_ii : tmp_ui;
    int*  __restrict__ tab = is_ii ? tab_ii : tab_ui;
    const int nnz = is_ii ? nnz_ii : nnz_ui;
    const int nb  = is_ii ? nb_ii : nb_ui;
    const unsigned char* __restrict__ flt = is_ii ? nullptr : filter;

    int t = threadIdx.x;
    for (int i = t; i < nb; i += blockDim.x) lcnt[i] = 0;
    __syncthreads();
    int beg = chunk_id * CHUNK, end = min(nnz, beg + CHUNK);
    // ---- count pass: 4-wide vector loads (16B aligned: beg is CHUNK-mult) ----
    for (int i = beg + 4 * t; i < end; i += 4 * blockDim.x) {
        if (i + 3 < end) {
            const int4 s4 = *(const int4*)(src + i);
            if (!flt) {
                atomicAdd(&lcnt[s4.x >> BSH], 1);
                atomicAdd(&lcnt[s4.y >> BSH], 1);
                atomicAdd(&lcnt[s4.z >> BSH], 1);
                atomicAdd(&lcnt[s4.w >> BSH], 1);
            } else {
                if (flt[s4.x]) atomicAdd(&lcnt[s4.x >> BSH], 1);
                if (flt[s4.y]) atomicAdd(&lcnt[s4.y >> BSH], 1);
                if (flt[s4.z]) atomicAdd(&lcnt[s4.z >> BSH], 1);
                if (flt[s4.w]) atomicAdd(&lcnt[s4.w >> BSH], 1);
            }
        } else {
            for (int k = i; k < end; k++) {
                int s = src[k];
                if (flt && !flt[s]) continue;
                atomicAdd(&lcnt[s >> BSH], 1);
            }
        }
    }
    __syncthreads();
    // wave 0: exclusive scan lcnt -> lbase[0..nb], lbase[nb] = total
    if (t < 64) {
        int carry = 0;
        for (int g = 0; g < nb; g += 64) {
            int i = g + t;
            int v = (i < nb) ? lcnt[i] : 0;
            int incl = v;
            #pragma unroll
            for (int m = 1; m < 64; m <<= 1) {
                int u = __shfl_up(incl, m, 64);
                if (t >= m) incl += u;
            }
            if (i < nb) lbase[i] = carry + incl - v;
            carry += __shfl(incl, 63, 64);
        }
        if (t == 0) lbase[nb] = carry;
    }
    __syncthreads();
    for (int i = t; i < nb; i += blockDim.x) lcur[i] = lbase[i];
    __syncthreads();
    // ---- bin pass: 4-wide (src,dst,val all in flight -> MLP 3) ----
    for (int i = beg + 4 * t; i < end; i += 4 * blockDim.x) {
        if (i + 3 < end) {
            const int4   s4 = *(const int4*)(src + i);
            const int4   d4 = *(const int4*)(dst + i);
            const float4 v4 = *(const float4*)(val + i);
            if (!flt || flt[s4.x]) {
                int pos = atomicAdd(&lcur[s4.x >> BSH], 1);
                stage[pos] = make_int2(d4.x | ((s4.x & (RPB - 1)) << 17), __float_as_int(v4.x));
            }
            if (!flt || flt[s4.y]) {
                int pos = atomicAdd(&lcur[s4.y >> BSH], 1);
                stage[pos] = make_int2(d4.y | ((s4.y & (RPB - 1)) << 17), __float_as_int(v4.y));
            }
            if (!flt || flt[s4.z]) {
                int pos = atomicAdd(&lcur[s4.z >> BSH], 1);
                stage[pos] = make_int2(d4.z | ((s4.z & (RPB - 1)) << 17), __float_as_int(v4.z));
            }
            if (!flt || flt[s4.w]) {
                int pos = atomicAdd(&lcur[s4.w >> BSH], 1);
                stage[pos] = make_int2(d4.w | ((s4.w & (RPB - 1)) << 17), __float_as_int(v4.w));
            }
        } else {
            for (int k = i; k < end; k++) {
                int s = src[k];
                if (flt && !flt[s]) continue;
                int pos = atomicAdd(&lcur[s >> BSH], 1);
                stage[pos] = make_int2(dst[k] | ((s & (RPB - 1)) << 17), __float_as_int(val[k]));
            }
        }
    }
    __syncthreads();
    // SEQUENTIAL flush (int4-wide): block-contiguous region + table row.
    // May copy one garbage int2 past total (stays within CHUNK, never read).
    int total = lbase[nb];
    int4* outp4 = (int4*)(tmp + (size_t)chunk_id * CHUNK);
    const int4* st4 = (const int4*)stage;
    int tot4 = (total + 1) >> 1;
    for (int i = t; i < tot4; i += blockDim.x) outp4[i] = st4[i];
    int* trow = tab + (size_t)chunk_id * (nb + 1);
    for (int i = t; i <= nb; i += blockDim.x) trow[i] = lbase[i];
}

// ---- pass B: block = bucket; gather segments via table, LDS sort, sequential write ----
__global__ void pass_b(const int2* __restrict__ tmp_ii, const int* __restrict__ tab_ii,
                       int nch_ii, unsigned int* __restrict__ edges_ii,
                       int* __restrict__ rp_ii, int* __restrict__ rpe_ii, int nb_ii,
                       const int2* __restrict__ tmp_ui, const int* __restrict__ tab_ui,
                       int nch_ui, unsigned int* __restrict__ edges_ui,
                       int* __restrict__ rp_ui, int* __restrict__ rpe_ui) {
    __shared__ int2 stage[STAGE_B];            // 36,864 B
    __shared__ unsigned int outs[STAGE_B];     // 18,432 B
    __shared__ int tsum[512];
    __shared__ int cnt[RPB];
    __shared__ int cur[RPB];
    __shared__ int sc[RPB];
    const bool is_ii = (blockIdx.x < (unsigned)nb_ii);
    const int b = is_ii ? blockIdx.x : (blockIdx.x - nb_ii);
    const int2* __restrict__ tmp = is_ii ? tmp_ii : tmp_ui;
    const int* __restrict__ tab = is_ii ? tab_ii : tab_ui;
    unsigned int* __restrict__ edges = is_ii ? edges_ii : edges_ui;
    int* __restrict__ rp  = is_ii ? rp_ii : rp_ui;
    int* __restrict__ rpe = is_ii ? rpe_ii : rpe_ui;
    const int nch = is_ii ? nch_ii : nch_ui;
    const int nbp1 = (is_ii ? nb_ii : (gridDim.x - nb_ii)) + 1;
    const int n_rows = is_ii ? MM : UU;
    const int cap_e = is_ii ? CAPE_II : CAPE_UI;

    int t = threadIdx.x;
    // phase 0: per-thread segment-length sums over assigned chunks
    int mysum = 0;
    for (int c = t; c < nch; c += 512)
        mysum += tab[(size_t)c * nbp1 + b + 1] - tab[(size_t)c * nbp1 + b];
    tsum[t] = mysum;
    __syncthreads();
    for (int off = 1; off < 512; off <<= 1) {
        int u = (t >= off) ? tsum[t - off] : 0;
        __syncthreads();
        tsum[t] += u;
        __syncthreads();
    }
    int mybase = tsum[t] - mysum;
    int total = tsum[511];
    // phase 1: gather segments into LDS stage (random ~84B reads, high MLP)
    for (int c = t; c < nch; c += 512) {
        int s0 = tab[(size_t)c * nbp1 + b];
        int s1 = tab[(size_t)c * nbp1 + b + 1];
        const int2* seg = tmp + (size_t)c * CHUNK + s0;
        for (int k = 0; k < s1 - s0; k++) stage[mybase++] = seg[k];
    }
    __syncthreads();
    // phase 2: row hist -> scan -> rp/rpe -> scatter to LDS out -> sequential store
    if (t < RPB) cnt[t] = 0;
    __syncthreads();
    for (int i = t; i < total; i += 512)
        atomicAdd(&cnt[(stage[i].x >> 17) & (RPB - 1)], 1);
    __syncthreads();
    int v = 0;
    if (t < RPB) { v = cnt[t]; sc[t] = v; }
    __syncthreads();
    for (int off = 1; off < RPB; off <<= 1) {
        int u = 0;
        if (t < RPB && t >= off) u = sc[t - off];
        __syncthreads();
        if (t < RPB) sc[t] += u;
        __syncthreads();
    }
    int ebeg = b * cap_e;
    if (t < RPB) {
        int excl = sc[t] - v;
        int r = (b << BSH) + t;
        if (r < n_rows) { rp[r] = ebeg + excl; rpe[r] = ebeg + excl + v; }
        cur[t] = excl;
    }
    __syncthreads();
    for (int i = t; i < total; i += 512) {
        int2 e = stage[i];
        int s = (e.x >> 17) & (RPB - 1);
        int pos = atomicAdd(&cur[s], 1);
        outs[pos] = ((unsigned int)(e.x & 0x1FFFF) << 15) | (f2bf(__int_as_float(e.y)) & 0x7FFFu);
    }
    __syncthreads();
    unsigned int* eg = edges + (size_t)ebeg;
    for (int i = t; i < total; i += 512) eg[i] = outs[i];
}

// ---- fp32 -> bf16 table conversion (fallback when conv not fused) ----
__global__ void conv_bf16(const float4* __restrict__ in, ushort4* __restrict__ out, int n4) {
    int i = blockIdx.x * blockDim.x + threadIdx.x;
    if (i >= n4) return;
    float4 v = in[i];
    ushort4 o;
    o.x = f2bf(v.x); o.y = f2bf(v.y); o.z = f2bf(v.z); o.w = f2bf(v.w);
    out[i] = o;
}

// ---- propagation SpMM: r18 dual-row quad-edge gather, bf16 acc (frozen) ----
template <bool WRITE_Y, bool INIT_ACC>
__global__ void spmm_bf16(const int* __restrict__ rp, const int* __restrict__ rpe,
                          const unsigned int* __restrict__ edges,
                          const unsigned short* __restrict__ xb, unsigned short* __restrict__ yb,
                          const unsigned short* __restrict__ e0b, unsigned short* __restrict__ accb,
                          const float* __restrict__ att, int layer, int n_rows) {
    int wid = (blockIdx.x * blockDim.x + threadIdx.x) >> 6;
    int lane = threadIdx.x & 63;
    int r0 = wid * 2;
    if (r0 >= n_rows) return;
    int r1 = r0 + 1;
    bool has1 = (r1 < n_rows);
    int q = lane >> 4, sub = lane & 15;
    int eA = rp[r0], endA = rpe[r0];
    int eB = has1 ? rp[r1] : 0, endB = has1 ? rpe[r1] : 0;
    float a0 = 0.f, a1 = 0.f, a2 = 0.f, a3 = 0.f;
    float b0 = 0.f, b1 = 0.f, b2 = 0.f, b3 = 0.f;
    while (eA < endA || eB < endB) {
        unsigned int evA = 0u, evB = 0u;
        int stepsA = 0, stepsB = 0;
        if (eA < endA) {
            int idx = eA + lane;
            evA = (idx < endA) ? edges[idx] : 0u;
            stepsA = (min(64, endA - eA) + 3) >> 2;
        }
        if (eB < endB) {
            int idx = eB + lane;
            evB = (idx < endB) ? edges[idx] : 0u;
            stepsB = (min(64, endB - eB) + 3) >> 2;
        }
        int steps = max(stepsA, stepsB);
        int jq = q;
        for (int st = 0; st < steps; ++st, jq += 4) {
            unsigned int pA = (st < stepsA) ? (unsigned)__shfl((int)evA, jq, 64) : 0u;
            unsigned int pB = (st < stepsB) ? (unsigned)__shfl((int)evB, jq, 64) : 0u;
            const uint2 uA = *((const uint2*)(xb + ((size_t)pk_dst(pA) << 6)) + sub);
            const uint2 uB = *((const uint2*)(xb + ((size_t)pk_dst(pB) << 6)) + sub);
            float vA = pk_val(pA);
            float vB = pk_val(pB);
            a0 = fmaf(vA, __uint_as_float(uA.x << 16), a0);
            a1 = fmaf(vA, __uint_as_float(uA.x & 0xFFFF0000u), a1);
            a2 = fmaf(vA, __uint_as_float(uA.y << 16), a2);
            a3 = fmaf(vA, __uint_as_float(uA.y & 0xFFFF0000u), a3);
            b0 = fmaf(vB, __uint_as_float(uB.x << 16), b0);
            b1 = fmaf(vB, __uint_as_float(uB.x & 0xFFFF0000u), b1);
            b2 = fmaf(vB, __uint_as_float(uB.y << 16), b2);
            b3 = fmaf(vB, __uint_as_float(uB.y & 0xFFFF0000u), b3);
        }
        eA += 64; eB += 64;
    }
    a0 += __shfl_xor(a0, 16, 64); a0 += __shfl_xor(a0, 32, 64);
    a1 += __shfl_xor(a1, 16, 64); a1 += __shfl_xor(a1, 32, 64);
    a2 += __shfl_xor(a2, 16, 64); a2 += __shfl_xor(a2, 32, 64);
    a3 += __shfl_xor(a3, 16, 64); a3 += __shfl_xor(a3, 32, 64);
    b0 += __shfl_xor(b0, 16, 64); b0 += __shfl_xor(b0, 32, 64);
    b1 += __shfl_xor(b1, 16, 64); b1 += __shfl_xor(b1, 32, 64);
    b2 += __shfl_xor(b2, 16, 64); b2 += __shfl_xor(b2, 32, 64);
    b3 += __shfl_xor(b3, 16, 64); b3 += __shfl_xor(b3, 32, 64);
    if (lane < 32 && (lane < 16 || has1)) {
        float s0 = (lane < 16) ? a0 : b0;
        float s1 = (lane < 16) ? a1 : b1;
        float s2 = (lane < 16) ? a2 : b2;
        float s3 = (lane < 16) ? a3 : b3;
        int r = (lane < 16) ? r0 : r1;
        float a = att[layer];
        s0 *= a; s1 *= a; s2 *= a; s3 *= a;
        size_t o = (size_t)r * DD + 4 * sub;
        if (WRITE_Y) {
            ushort4 yv = make_ushort4(f2bf(s0), f2bf(s1), f2bf(s2), f2bf(s3));
            *(ushort4*)(yb + o) = yv;
        }
        const uint2 u0 = *(const uint2*)((INIT_ACC ? e0b : accb) + o);
        s0 += __uint_as_float(u0.x << 16);
        s1 += __uint_as_float(u0.x & 0xFFFF0000u);
        s2 += __uint_as_float(u0.y << 16);
        s3 += __uint_as_float(u0.y & 0xFFFF0000u);
        *(ushort4*)(accb + o) = make_ushort4(f2bf(s0), f2bf(s1), f2bf(s2), f2bf(s3));
    }
}

__global__ void set_bitmap(const int* __restrict__ users, unsigned char* __restrict__ bm, int B) {
    int i = blockIdx.x * blockDim.x + threadIdx.x;
    if (i < B) bm[users[i]] = 1;
}

// fused UI-SpMM + pair dot: quad-edge gather over bf16 acc table (frozen)
__global__ void user_dot_kernel(const int* __restrict__ users, const int* __restrict__ items,
                                const int* __restrict__ rp, const int* __restrict__ rpe,
                                const unsigned int* __restrict__ edges,
                                const unsigned short* __restrict__ accb,
                                float* __restrict__ out, int B) {
    int w = (blockIdx.x * blockDim.x + threadIdx.x) >> 6;
    int lane = threadIdx.x & 63;
    if (w >= B) return;
    int q = lane >> 4, sub = lane & 15;
    int u = users[w];
    int beg = rp[u], end = rpe[u];
    float s0 = 0.f, s1 = 0.f, s2 = 0.f, s3 = 0.f;
    for (int e = beg; e < end; e += 64) {
        int idx = e + lane;
        unsigned int ev = (idx < end) ? edges[idx] : 0u;
        int cnt = min(64, end - e);
        int steps = (cnt + 3) >> 2;
        int jq = q;
        for (int st = 0; st < steps; ++st, jq += 4) {
            unsigned int p = (unsigned)__shfl((int)ev, jq, 64);
            float v = pk_val(p);
            const uint2 x = *((const uint2*)(accb + ((size_t)pk_dst(p) << 6)) + sub);
            s0 = fmaf(v, __uint_as_float(x.x << 16), s0);
            s1 = fmaf(v, __uint_as_float(x.x & 0xFFFF0000u), s1);
            s2 = fmaf(v, __uint_as_float(x.y << 16), s2);
            s3 = fmaf(v, __uint_as_float(x.y & 0xFFFF0000u), s3);
        }
    }
    s0 += __shfl_xor(s0, 16, 64); s0 += __shfl_xor(s0, 32, 64);
    s1 += __shfl_xor(s1, 16, 64); s1 += __shfl_xor(s1, 32, 64);
    s2 += __shfl_xor(s2, 16, 64); s2 += __shfl_xor(s2, 32, 64);
    s3 += __shfl_xor(s3, 16, 64); s3 += __shfl_xor(s3, 32, 64);
    float p = 0.f;
    if (lane < 16) {
        const uint2 iu = *((const uint2*)(accb + ((size_t)items[w] << 6)) + sub);
        p = s0 * __uint_as_float(iu.x << 16)
          + s1 * __uint_as_float(iu.x & 0xFFFF0000u)
          + s2 * __uint_as_float(iu.y << 16)
          + s3 * __uint_as_float(iu.y & 0xFFFF0000u);
        #pragma unroll
        for (int m = 8; m >= 1; m >>= 1) p += __shfl_xor(p, m, 64);
        if (sub == 0) out[w] = p * 0.0625f;   // (1/4 mean) each side
    }
}

extern "C" void kernel_launch(void* const* d_in, const int* in_sizes, int n_in,
                              void* d_out, int out_size, void* d_ws, size_t ws_size,
                              hipStream_t stream) {
    const int*   users    = (const int*)d_in[0];
    const int*   items    = (const int*)d_in[1];
    const int*   ii_src   = (const int*)d_in[2];
    const int*   ii_dst   = (const int*)d_in[3];
    const float* ii_val   = (const float*)d_in[4];
    const int*   ui_src   = (const int*)d_in[5];
    const int*   ui_dst   = (const int*)d_in[6];
    const float* ui_val   = (const float*)d_in[7];
    const float* item_emb = (const float*)d_in[8];
    const float* att      = (const float*)d_in[9];

    const int E_ii = in_sizes[2];
    const int E_ui = in_sizes[5];
    const int B    = in_sizes[0];
    const int NB_ii = (MM + RPB - 1) / RPB;              // 782
    const int NB_ui = (UU + RPB - 1) / RPB;              // 391
    const int nchunks_ii = (E_ii + CHUNK - 1) / CHUNK;   // 782
    const int nchunks_ui = (E_ui + CHUNK - 1) / CHUNK;   // 391

    char* w = (char*)d_ws;
    // tmp_ii 782*4096*8 = 25,624,576; after pass_b overlaid by y1 (and xb0 in
    // fallback mode)
    int2*  tmp_ii = (int2*)(w);
    unsigned short* xb0_old = (unsigned short*)(w);               // 12.8 MB (fallback)
    unsigned short* y1  = (unsigned short*)(w + 12800000);        // 12.8 MB
    // tmp_ui 391*4096*8 = 12,812,288 @25,624,576; overlaid by y2 (12.8 MB)
    int2*  tmp_ui = (int2*)(w + 25624576);
    unsigned short* y2  = (unsigned short*)(w + 25624576);
    unsigned short* accb = (unsigned short*)(w + 38436864);       // 12.8 MB bf16
    unsigned int* edges_ii = (unsigned int*)(w + 51236864);       // 782*4608*4 = 14,413,824
    unsigned int* edges_ui = (unsigned int*)(w + 65650688);       // 391*1024*4 = 1,601,536
    int*   tab_ii = (int*)(w + 67252224);                         // 782*783*4 = 2,449,224
    int*   tab_ui = (int*)(w + 69701448);                         // 391*392*4 = 613,088
    int*   rp_ii  = (int*)(w + 70314536);                         // (MM+2)*4
    int*   rpe_ii = (int*)(w + 70714544);
    int*   rp_ui  = (int*)(w + 71114552);                         // (UU+2)*4
    int*   rpe_ui = (int*)(w + 71314560);
    unsigned char* bitmap = (unsigned char*)(w + 71514568);       // UU bytes
    // fused-conv mode: xb0 in fresh region (no tmp_ii overlay) so conv can run
    // concurrently with pass_a binning blocks. 4096-ALIGNED offset: r24 used
    // 71,564,576 = 32 mod 128 -> every 128B row gather straddled 2 lines,
    // doubling layer-0 spmm FETCH (154->293MB, 60->87.7us).
    unsigned short* xb0_new = (unsigned short*)(w + 71565312);    // 12.8 MB, 4K-aligned
    const size_t ws_need_fused = 71565312 + 12800000;             // 84,365,312
    const bool fuse_conv = (ws_size >= ws_need_fused);
    unsigned short* xb0 = fuse_conv ? xb0_new : xb0_old;

    const int TB = 256;
    const int TBB = 512;
    const size_t smem_a = CHUNK * 8 + (3 * NBMAX + 8) * 4;   // ~42.4 KB -> 3 blocks/CU
    const int n4 = MM * DD / 4;                              // 1,600,000 float4s
    const int nconv = fuse_conv ? (n4 + 1023) / 1024 : 0;    // 1563 tail blocks

    // ---- bitmap memset + set ----
    hipMemsetAsync(bitmap, 0, UU, stream);
    set_bitmap<<<(B + TB - 1) / TB, TB, 0, stream>>>(users, bitmap, B);

    // ---- both graphs: binning (sequential flush) + fused conv tail ----
    pass_a<<<nchunks_ii + nchunks_ui + nconv, TBB, smem_a, stream>>>(
        ii_src, ii_dst, ii_val, tmp_ii, tab_ii, E_ii, NB_ii, nchunks_ii,
        ui_src, ui_dst, ui_val, tmp_ui, tab_ui, E_ui, NB_ui, nchunks_ui, bitmap,
        (const float4*)item_emb, (ushort4*)xb0, n4);
    pass_b<<<NB_ii + NB_ui, TBB, 0, stream>>>(
        tmp_ii, tab_ii, nchunks_ii, edges_ii, rp_ii, rpe_ii, NB_ii,
        tmp_ui, tab_ui, nchunks_ui, edges_ui, rp_ui, rpe_ui);

    // ---- bf16 x0 fallback conversion (only when not fused), 3 layers ----
    if (!fuse_conv)
        conv_bf16<<<(n4 + TB - 1) / TB, TB, 0, stream>>>((const float4*)item_emb, (ushort4*)xb0, n4);
    const int nwaves = (MM + 1) / 2;                      // dual-row waves
    const int ii_blocks = (nwaves * 64 + TB - 1) / TB;
    spmm_bf16<true,  true ><<<ii_blocks, TB, 0, stream>>>(rp_ii, rpe_ii, edges_ii, xb0, y1, xb0, accb, att, 0, MM);
    spmm_bf16<true,  false><<<ii_blocks, TB, 0, stream>>>(rp_ii, rpe_ii, edges_ii, y1,  y2, nullptr, accb, att, 1, MM);
    spmm_bf16<false, false><<<ii_blocks, TB, 0, stream>>>(rp_ii, rpe_ii, edges_ii, y2,  nullptr, nullptr, accb, att, 2, MM);

    // ---- fused user aggregation + pair dot ----
    user_dot_kernel<<<(B * 64 + TB - 1) / TB, TB, 0, stream>>>(users, items, rp_ui, rpe_ui, edges_ui, accb,
                                                               (float*)d_out, B);
}

// Round 8
// 358.763 us; speedup vs baseline: 1.1109x; 1.0285x over previous
//
#include <hip/hip_runtime.h>

// LightGCN on MI355X, round 26.
// r23: pass_a 4-wide vectorized -> 385.4. r24: conv fused into pass_a but
//      xb0 misaligned (32 mod 128: every row gather straddled 2 lines,
//      L0 spmm 60->87.7us) -> 398.6. r25: 4K-aligned xb0 -> 369.0 (best).
//      spmm closed at ~58.4us x3 (beyond-L2 transaction-rate floor).
// r26: attack pass_b phase-1. Its ~764K random segment gathers (avg 42B)
//      from tmp are L3 transactions (tmp written on other XCDs; L2s not
//      coherent -> kernel-end writeback) at the SAME ~1.1 tx/cy/XCD ceiling
//      as spmm => ~40-50us. CHUNK 4096->8192 halves segment count (84B avg).
//      r22's 8192 failure causes are fixed: pass_a loops now 4-wide
//      vectorized (r22 was scalar, VGPR=8), and the 1563 fused conv blocks
//      fill the 587-block grid's 15% tail at 2 blocks/CU. pass_b gather also
//      int4-vectorized (16B-aligned after odd-start peel).
// Predict: spmm unchanged ~58.4/157MB (canary), pass_a < 50 (out of top-5),
//      pass_b -15..-20us, total ~350-358. Flat => structural floor, declare
//      roofline next round.

#define MM 100000
#define UU 50000
#define DD 64
#define RPB 128           // rows per bucket
#define BSH 7
#define NBMAX 800
#define CHUNK 8192
#define STAGE_B 4608      // pass_b stage entries (= CAPE_II)
#define CAPE_II 4608      // edges stride II
#define CAPE_UI 1024      // edges stride UI

__device__ __forceinline__ unsigned short f2bf(float f) {
    unsigned int b = __float_as_uint(f);
    b += 0x7FFF + ((b >> 16) & 1);          // round-to-nearest-even
    return (unsigned short)(b >> 16);
}
// packed edge: (dst << 15) | (bf16(val) & 0x7FFF); val >= 0 so sign bit unused
__device__ __forceinline__ float pk_val(unsigned int w) {
    return __uint_as_float((w & 0x7FFFu) << 16);
}
__device__ __forceinline__ int pk_dst(unsigned int w) { return (int)(w >> 15); }

// ---- pass A (+ fused conv tail blocks) ----
__global__ void pass_a(const int* __restrict__ src_ii, const int* __restrict__ dst_ii,
                       const float* __restrict__ val_ii, int2* __restrict__ tmp_ii,
                       int* __restrict__ tab_ii, int nnz_ii, int nb_ii, int nchunks_ii,
                       const int* __restrict__ src_ui, const int* __restrict__ dst_ui,
                       const float* __restrict__ val_ui, int2* __restrict__ tmp_ui,
                       int* __restrict__ tab_ui, int nnz_ui, int nb_ui, int nchunks_ui,
                       const unsigned char* __restrict__ filter,
                       const float4* __restrict__ conv_in, ushort4* __restrict__ conv_out,
                       int n4) {
    extern __shared__ char smem[];
    const int nbin_blocks = nchunks_ii + nchunks_ui;
    int cb = (int)blockIdx.x - nbin_blocks;
    if (cb >= 0) {                               // ---- fused conv tail ----
        int i = cb * 1024 + (int)threadIdx.x;
        if (i < n4) {
            float4 v = conv_in[i];
            conv_out[i] = make_ushort4(f2bf(v.x), f2bf(v.y), f2bf(v.z), f2bf(v.w));
        }
        i += 512;
        if (i < n4) {
            float4 v = conv_in[i];
            conv_out[i] = make_ushort4(f2bf(v.x), f2bf(v.y), f2bf(v.z), f2bf(v.w));
        }
        return;
    }
    int2* stage = (int2*)smem;                     // CHUNK entries (64 KB)
    int*  lcnt  = (int*)(smem + CHUNK * 8);        // NBMAX
    int*  lbase = lcnt + NBMAX;                    // NBMAX+1
    int*  lcur  = lbase + NBMAX + 1;               // NBMAX
    const bool is_ii = (blockIdx.x < (unsigned)nchunks_ii);
    const int chunk_id = is_ii ? blockIdx.x : (blockIdx.x - nchunks_ii);
    const int* __restrict__ src = is_ii ? src_ii : src_ui;
    const int* __restrict__ dst = is_ii ? dst_ii : dst_ui;
    const float* __restrict__ val = is_ii ? val_ii : val_ui;
    int2* __restrict__ tmp = is_ii ? tmp_ii : tmp_ui;
    int*  __restrict__ tab = is_ii ? tab_ii : tab_ui;
    const int nnz = is_ii ? nnz_ii : nnz_ui;
    const int nb  = is_ii ? nb_ii : nb_ui;
    const unsigned char* __restrict__ flt = is_ii ? nullptr : filter;

    int t = threadIdx.x;
    for (int i = t; i < nb; i += blockDim.x) lcnt[i] = 0;
    __syncthreads();
    int beg = chunk_id * CHUNK, end = min(nnz, beg + CHUNK);
    // ---- count pass: 4-wide vector loads (16B aligned: beg is CHUNK-mult) ----
    for (int i = beg + 4 * t; i < end; i += 4 * blockDim.x) {
        if (i + 3 < end) {
            const int4 s4 = *(const int4*)(src + i);
            if (!flt) {
                atomicAdd(&lcnt[s4.x >> BSH], 1);
                atomicAdd(&lcnt[s4.y >> BSH], 1);
                atomicAdd(&lcnt[s4.z >> BSH], 1);
                atomicAdd(&lcnt[s4.w >> BSH], 1);
            } else {
                if (flt[s4.x]) atomicAdd(&lcnt[s4.x >> BSH], 1);
                if (flt[s4.y]) atomicAdd(&lcnt[s4.y >> BSH], 1);
                if (flt[s4.z]) atomicAdd(&lcnt[s4.z >> BSH], 1);
                if (flt[s4.w]) atomicAdd(&lcnt[s4.w >> BSH], 1);
            }
        } else {
            for (int k = i; k < end; k++) {
                int s = src[k];
                if (flt && !flt[s]) continue;
                atomicAdd(&lcnt[s >> BSH], 1);
            }
        }
    }
    __syncthreads();
    // wave 0: exclusive scan lcnt -> lbase[0..nb], lbase[nb] = total
    if (t < 64) {
        int carry = 0;
        for (int g = 0; g < nb; g += 64) {
            int i = g + t;
            int v = (i < nb) ? lcnt[i] : 0;
            int incl = v;
            #pragma unroll
            for (int m = 1; m < 64; m <<= 1) {
                int u = __shfl_up(incl, m, 64);
                if (t >= m) incl += u;
            }
            if (i < nb) lbase[i] = carry + incl - v;
            carry += __shfl(incl, 63, 64);
        }
        if (t == 0) lbase[nb] = carry;
    }
    __syncthreads();
    for (int i = t; i < nb; i += blockDim.x) lcur[i] = lbase[i];
    __syncthreads();
    // ---- bin pass: 4-wide (src,dst,val all in flight -> MLP 3) ----
    for (int i = beg + 4 * t; i < end; i += 4 * blockDim.x) {
        if (i + 3 < end) {
            const int4   s4 = *(const int4*)(src + i);
            const int4   d4 = *(const int4*)(dst + i);
            const float4 v4 = *(const float4*)(val + i);
            if (!flt || flt[s4.x]) {
                int pos = atomicAdd(&lcur[s4.x >> BSH], 1);
                stage[pos] = make_int2(d4.x | ((s4.x & (RPB - 1)) << 17), __float_as_int(v4.x));
            }
            if (!flt || flt[s4.y]) {
                int pos = atomicAdd(&lcur[s4.y >> BSH], 1);
                stage[pos] = make_int2(d4.y | ((s4.y & (RPB - 1)) << 17), __float_as_int(v4.y));
            }
            if (!flt || flt[s4.z]) {
                int pos = atomicAdd(&lcur[s4.z >> BSH], 1);
                stage[pos] = make_int2(d4.z | ((s4.z & (RPB - 1)) << 17), __float_as_int(v4.z));
            }
            if (!flt || flt[s4.w]) {
                int pos = atomicAdd(&lcur[s4.w >> BSH], 1);
                stage[pos] = make_int2(d4.w | ((s4.w & (RPB - 1)) << 17), __float_as_int(v4.w));
            }
        } else {
            for (int k = i; k < end; k++) {
                int s = src[k];
                if (flt && !flt[s]) continue;
                int pos = atomicAdd(&lcur[s >> BSH], 1);
                stage[pos] = make_int2(dst[k] | ((s & (RPB - 1)) << 17), __float_as_int(val[k]));
            }
        }
    }
    __syncthreads();
    // SEQUENTIAL flush (int4-wide): block-contiguous region + table row.
    // May copy one garbage int2 past total (stays within CHUNK, never read).
    int total = lbase[nb];
    int4* outp4 = (int4*)(tmp + (size_t)chunk_id * CHUNK);
    const int4* st4 = (const int4*)stage;
    int tot4 = (total + 1) >> 1;
    for (int i = t; i < tot4; i += blockDim.x) outp4[i] = st4[i];
    int* trow = tab + (size_t)chunk_id * (nb + 1);
    for (int i = t; i <= nb; i += blockDim.x) trow[i] = lbase[i];
}

// ---- pass B: block = bucket; gather segments via table, LDS sort, sequential write ----
__global__ void pass_b(const int2* __restrict__ tmp_ii, const int* __restrict__ tab_ii,
                       int nch_ii, unsigned int* __restrict__ edges_ii,
                       int* __restrict__ rp_ii, int* __restrict__ rpe_ii, int nb_ii,
                       const int2* __restrict__ tmp_ui, const int* __restrict__ tab_ui,
                       int nch_ui, unsigned int* __restrict__ edges_ui,
                       int* __restrict__ rp_ui, int* __restrict__ rpe_ui) {
    __shared__ int2 stage[STAGE_B];            // 36,864 B
    __shared__ unsigned int outs[STAGE_B];     // 18,432 B
    __shared__ int tsum[512];
    __shared__ int cnt[RPB];
    __shared__ int cur[RPB];
    __shared__ int sc[RPB];
    const bool is_ii = (blockIdx.x < (unsigned)nb_ii);
    const int b = is_ii ? blockIdx.x : (blockIdx.x - nb_ii);
    const int2* __restrict__ tmp = is_ii ? tmp_ii : tmp_ui;
    const int* __restrict__ tab = is_ii ? tab_ii : tab_ui;
    unsigned int* __restrict__ edges = is_ii ? edges_ii : edges_ui;
    int* __restrict__ rp  = is_ii ? rp_ii : rp_ui;
    int* __restrict__ rpe = is_ii ? rpe_ii : rpe_ui;
    const int nch = is_ii ? nch_ii : nch_ui;
    const int nbp1 = (is_ii ? nb_ii : (gridDim.x - nb_ii)) + 1;
    const int n_rows = is_ii ? MM : UU;
    const int cap_e = is_ii ? CAPE_II : CAPE_UI;

    int t = threadIdx.x;
    // phase 0: per-thread segment-length sums over assigned chunks
    int mysum = 0;
    for (int c = t; c < nch; c += 512)
        mysum += tab[(size_t)c * nbp1 + b + 1] - tab[(size_t)c * nbp1 + b];
    tsum[t] = mysum;
    __syncthreads();
    for (int off = 1; off < 512; off <<= 1) {
        int u = (t >= off) ? tsum[t - off] : 0;
        __syncthreads();
        tsum[t] += u;
        __syncthreads();
    }
    int mybase = tsum[t] - mysum;
    int total = tsum[511];
    // phase 1: gather segments (avg ~84B @ CHUNK 8192) into LDS stage.
    // int4-vectorized: peel odd start so (seg+k) is 16B aligned.
    for (int c = t; c < nch; c += 512) {
        int s0 = tab[(size_t)c * nbp1 + b];
        int s1 = tab[(size_t)c * nbp1 + b + 1];
        const int2* seg = tmp + (size_t)c * CHUNK + s0;
        int len = s1 - s0;
        int k = 0;
        if ((s0 & 1) && len > 0) { stage[mybase++] = seg[0]; k = 1; }
        for (; k + 1 < len; k += 2) {
            const int4 two = *(const int4*)(seg + k);
            stage[mybase++] = make_int2(two.x, two.y);
            stage[mybase++] = make_int2(two.z, two.w);
        }
        if (k < len) stage[mybase++] = seg[k];
    }
    __syncthreads();
    // phase 2: row hist -> scan -> rp/rpe -> scatter to LDS out -> sequential store
    if (t < RPB) cnt[t] = 0;
    __syncthreads();
    for (int i = t; i < total; i += 512)
        atomicAdd(&cnt[(stage[i].x >> 17) & (RPB - 1)], 1);
    __syncthreads();
    int v = 0;
    if (t < RPB) { v = cnt[t]; sc[t] = v; }
    __syncthreads();
    for (int off = 1; off < RPB; off <<= 1) {
        int u = 0;
        if (t < RPB && t >= off) u = sc[t - off];
        __syncthreads();
        if (t < RPB) sc[t] += u;
        __syncthreads();
    }
    int ebeg = b * cap_e;
    if (t < RPB) {
        int excl = sc[t] - v;
        int r = (b << BSH) + t;
        if (r < n_rows) { rp[r] = ebeg + excl; rpe[r] = ebeg + excl + v; }
        cur[t] = excl;
    }
    __syncthreads();
    for (int i = t; i < total; i += 512) {
        int2 e = stage[i];
        int s = (e.x >> 17) & (RPB - 1);
        int pos = atomicAdd(&cur[s], 1);
        outs[pos] = ((unsigned int)(e.x & 0x1FFFF) << 15) | (f2bf(__int_as_float(e.y)) & 0x7FFFu);
    }
    __syncthreads();
    unsigned int* eg = edges + (size_t)ebeg;
    for (int i = t; i < total; i += 512) eg[i] = outs[i];
}

// ---- fp32 -> bf16 table conversion (fallback when conv not fused) ----
__global__ void conv_bf16(const float4* __restrict__ in, ushort4* __restrict__ out, int n4) {
    int i = blockIdx.x * blockDim.x + threadIdx.x;
    if (i >= n4) return;
    float4 v = in[i];
    ushort4 o;
    o.x = f2bf(v.x); o.y = f2bf(v.y); o.z = f2bf(v.z); o.w = f2bf(v.w);
    out[i] = o;
}

// ---- propagation SpMM: r18 dual-row quad-edge gather, bf16 acc (frozen) ----
template <bool WRITE_Y, bool INIT_ACC>
__global__ void spmm_bf16(const int* __restrict__ rp, const int* __restrict__ rpe,
                          const unsigned int* __restrict__ edges,
                          const unsigned short* __restrict__ xb, unsigned short* __restrict__ yb,
                          const unsigned short* __restrict__ e0b, unsigned short* __restrict__ accb,
                          const float* __restrict__ att, int layer, int n_rows) {
    int wid = (blockIdx.x * blockDim.x + threadIdx.x) >> 6;
    int lane = threadIdx.x & 63;
    int r0 = wid * 2;
    if (r0 >= n_rows) return;
    int r1 = r0 + 1;
    bool has1 = (r1 < n_rows);
    int q = lane >> 4, sub = lane & 15;
    int eA = rp[r0], endA = rpe[r0];
    int eB = has1 ? rp[r1] : 0, endB = has1 ? rpe[r1] : 0;
    float a0 = 0.f, a1 = 0.f, a2 = 0.f, a3 = 0.f;
    float b0 = 0.f, b1 = 0.f, b2 = 0.f, b3 = 0.f;
    while (eA < endA || eB < endB) {
        unsigned int evA = 0u, evB = 0u;
        int stepsA = 0, stepsB = 0;
        if (eA < endA) {
            int idx = eA + lane;
            evA = (idx < endA) ? edges[idx] : 0u;
            stepsA = (min(64, endA - eA) + 3) >> 2;
        }
        if (eB < endB) {
            int idx = eB + lane;
            evB = (idx < endB) ? edges[idx] : 0u;
            stepsB = (min(64, endB - eB) + 3) >> 2;
        }
        int steps = max(stepsA, stepsB);
        int jq = q;
        for (int st = 0; st < steps; ++st, jq += 4) {
            unsigned int pA = (st < stepsA) ? (unsigned)__shfl((int)evA, jq, 64) : 0u;
            unsigned int pB = (st < stepsB) ? (unsigned)__shfl((int)evB, jq, 64) : 0u;
            const uint2 uA = *((const uint2*)(xb + ((size_t)pk_dst(pA) << 6)) + sub);
            const uint2 uB = *((const uint2*)(xb + ((size_t)pk_dst(pB) << 6)) + sub);
            float vA = pk_val(pA);
            float vB = pk_val(pB);
            a0 = fmaf(vA, __uint_as_float(uA.x << 16), a0);
            a1 = fmaf(vA, __uint_as_float(uA.x & 0xFFFF0000u), a1);
            a2 = fmaf(vA, __uint_as_float(uA.y << 16), a2);
            a3 = fmaf(vA, __uint_as_float(uA.y & 0xFFFF0000u), a3);
            b0 = fmaf(vB, __uint_as_float(uB.x << 16), b0);
            b1 = fmaf(vB, __uint_as_float(uB.x & 0xFFFF0000u), b1);
            b2 = fmaf(vB, __uint_as_float(uB.y << 16), b2);
            b3 = fmaf(vB, __uint_as_float(uB.y & 0xFFFF0000u), b3);
        }
        eA += 64; eB += 64;
    }
    a0 += __shfl_xor(a0, 16, 64); a0 += __shfl_xor(a0, 32, 64);
    a1 += __shfl_xor(a1, 16, 64); a1 += __shfl_xor(a1, 32, 64);
    a2 += __shfl_xor(a2, 16, 64); a2 += __shfl_xor(a2, 32, 64);
    a3 += __shfl_xor(a3, 16, 64); a3 += __shfl_xor(a3, 32, 64);
    b0 += __shfl_xor(b0, 16, 64); b0 += __shfl_xor(b0, 32, 64);
    b1 += __shfl_xor(b1, 16, 64); b1 += __shfl_xor(b1, 32, 64);
    b2 += __shfl_xor(b2, 16, 64); b2 += __shfl_xor(b2, 32, 64);
    b3 += __shfl_xor(b3, 16, 64); b3 += __shfl_xor(b3, 32, 64);
    if (lane < 32 && (lane < 16 || has1)) {
        float s0 = (lane < 16) ? a0 : b0;
        float s1 = (lane < 16) ? a1 : b1;
        float s2 = (lane < 16) ? a2 : b2;
        float s3 = (lane < 16) ? a3 : b3;
        int r = (lane < 16) ? r0 : r1;
        float a = att[layer];
        s0 *= a; s1 *= a; s2 *= a; s3 *= a;
        size_t o = (size_t)r * DD + 4 * sub;
        if (WRITE_Y) {
            ushort4 yv = make_ushort4(f2bf(s0), f2bf(s1), f2bf(s2), f2bf(s3));
            *(ushort4*)(yb + o) = yv;
        }
        const uint2 u0 = *(const uint2*)((INIT_ACC ? e0b : accb) + o);
        s0 += __uint_as_float(u0.x << 16);
        s1 += __uint_as_float(u0.x & 0xFFFF0000u);
        s2 += __uint_as_float(u0.y << 16);
        s3 += __uint_as_float(u0.y & 0xFFFF0000u);
        *(ushort4*)(accb + o) = make_ushort4(f2bf(s0), f2bf(s1), f2bf(s2), f2bf(s3));
    }
}

__global__ void set_bitmap(const int* __restrict__ users, unsigned char* __restrict__ bm, int B) {
    int i = blockIdx.x * blockDim.x + threadIdx.x;
    if (i < B) bm[users[i]] = 1;
}

// fused UI-SpMM + pair dot: quad-edge gather over bf16 acc table (frozen)
__global__ void user_dot_kernel(const int* __restrict__ users, const int* __restrict__ items,
                                const int* __restrict__ rp, const int* __restrict__ rpe,
                                const unsigned int* __restrict__ edges,
                                const unsigned short* __restrict__ accb,
                                float* __restrict__ out, int B) {
    int w = (blockIdx.x * blockDim.x + threadIdx.x) >> 6;
    int lane = threadIdx.x & 63;
    if (w >= B) return;
    int q = lane >> 4, sub = lane & 15;
    int u = users[w];
    int beg = rp[u], end = rpe[u];
    float s0 = 0.f, s1 = 0.f, s2 = 0.f, s3 = 0.f;
    for (int e = beg; e < end; e += 64) {
        int idx = e + lane;
        unsigned int ev = (idx < end) ? edges[idx] : 0u;
        int cnt = min(64, end - e);
        int steps = (cnt + 3) >> 2;
        int jq = q;
        for (int st = 0; st < steps; ++st, jq += 4) {
            unsigned int p = (unsigned)__shfl((int)ev, jq, 64);
            float v = pk_val(p);
            const uint2 x = *((const uint2*)(accb + ((size_t)pk_dst(p) << 6)) + sub);
            s0 = fmaf(v, __uint_as_float(x.x << 16), s0);
            s1 = fmaf(v, __uint_as_float(x.x & 0xFFFF0000u), s1);
            s2 = fmaf(v, __uint_as_float(x.y << 16), s2);
            s3 = fmaf(v, __uint_as_float(x.y & 0xFFFF0000u), s3);
        }
    }
    s0 += __shfl_xor(s0, 16, 64); s0 += __shfl_xor(s0, 32, 64);
    s1 += __shfl_xor(s1, 16, 64); s1 += __shfl_xor(s1, 32, 64);
    s2 += __shfl_xor(s2, 16, 64); s2 += __shfl_xor(s2, 32, 64);
    s3 += __shfl_xor(s3, 16, 64); s3 += __shfl_xor(s3, 32, 64);
    float p = 0.f;
    if (lane < 16) {
        const uint2 iu = *((const uint2*)(accb + ((size_t)items[w] << 6)) + sub);
        p = s0 * __uint_as_float(iu.x << 16)
          + s1 * __uint_as_float(iu.x & 0xFFFF0000u)
          + s2 * __uint_as_float(iu.y << 16)
          + s3 * __uint_as_float(iu.y & 0xFFFF0000u);
        #pragma unroll
        for (int m = 8; m >= 1; m >>= 1) p += __shfl_xor(p, m, 64);
        if (sub == 0) out[w] = p * 0.0625f;   // (1/4 mean) each side
    }
}

extern "C" void kernel_launch(void* const* d_in, const int* in_sizes, int n_in,
                              void* d_out, int out_size, void* d_ws, size_t ws_size,
                              hipStream_t stream) {
    const int*   users    = (const int*)d_in[0];
    const int*   items    = (const int*)d_in[1];
    const int*   ii_src   = (const int*)d_in[2];
    const int*   ii_dst   = (const int*)d_in[3];
    const float* ii_val   = (const float*)d_in[4];
    const int*   ui_src   = (const int*)d_in[5];
    const int*   ui_dst   = (const int*)d_in[6];
    const float* ui_val   = (const float*)d_in[7];
    const float* item_emb = (const float*)d_in[8];
    const float* att      = (const float*)d_in[9];

    const int E_ii = in_sizes[2];
    const int E_ui = in_sizes[5];
    const int B    = in_sizes[0];
    const int NB_ii = (MM + RPB - 1) / RPB;              // 782
    const int NB_ui = (UU + RPB - 1) / RPB;              // 391
    const int nchunks_ii = (E_ii + CHUNK - 1) / CHUNK;   // 391 @ CHUNK=8192
    const int nchunks_ui = (E_ui + CHUNK - 1) / CHUNK;   // 196

    char* w = (char*)d_ws;
    // tmp_ii 391*8192*8 = 25,624,576; after pass_b overlaid by y1 (and xb0 in
    // fallback mode)
    int2*  tmp_ii = (int2*)(w);
    unsigned short* xb0_old = (unsigned short*)(w);               // 12.8 MB (fallback)
    unsigned short* y1  = (unsigned short*)(w + 12800000);        // 12.8 MB
    // tmp_ui 196*8192*8 = 12,845,056 @25,624,576; overlaid by y2 (12.8 MB)
    int2*  tmp_ui = (int2*)(w + 25624576);
    unsigned short* y2  = (unsigned short*)(w + 25624576);
    unsigned short* accb = (unsigned short*)(w + 38469632);       // 12.8 MB bf16
    unsigned int* edges_ii = (unsigned int*)(w + 51269632);       // 782*4608*4 = 14,413,824
    unsigned int* edges_ui = (unsigned int*)(w + 65683456);       // 391*1024*4 = 1,601,536
    int*   tab_ii = (int*)(w + 67284992);                         // 391*783*4 = 1,224,612
    int*   tab_ui = (int*)(w + 68509604);                         // 196*392*4 = 307,328
    int*   rp_ii  = (int*)(w + 68816932);                         // MM*4
    int*   rpe_ii = (int*)(w + 69216932);
    int*   rp_ui  = (int*)(w + 69616932);                         // UU*4
    int*   rpe_ui = (int*)(w + 69816932);
    unsigned char* bitmap = (unsigned char*)(w + 70016932);       // UU bytes
    // fused-conv mode: xb0 in fresh region, 4096-ALIGNED (r24 lesson: 32 mod
    // 128 offset doubled L0 spmm line traffic).
    unsigned short* xb0_new = (unsigned short*)(w + 70070272);    // 12.8 MB, 4K-aligned
    const size_t ws_need_fused = 70070272 + 12800000;             // 82,870,272
    const bool fuse_conv = (ws_size >= ws_need_fused);
    unsigned short* xb0 = fuse_conv ? xb0_new : xb0_old;

    const int TB = 256;
    const int TBB = 512;
    const size_t smem_a = CHUNK * 8 + (3 * NBMAX + 8) * 4;   // ~75.2 KB -> 2 blocks/CU
    const int n4 = MM * DD / 4;                              // 1,600,000 float4s
    const int nconv = fuse_conv ? (n4 + 1023) / 1024 : 0;    // 1563 tail blocks

    // ---- bitmap memset + set ----
    hipMemsetAsync(bitmap, 0, UU, stream);
    set_bitmap<<<(B + TB - 1) / TB, TB, 0, stream>>>(users, bitmap, B);

    // ---- both graphs: binning (sequential flush) + fused conv tail ----
    pass_a<<<nchunks_ii + nchunks_ui + nconv, TBB, smem_a, stream>>>(
        ii_src, ii_dst, ii_val, tmp_ii, tab_ii, E_ii, NB_ii, nchunks_ii,
        ui_src, ui_dst, ui_val, tmp_ui, tab_ui, E_ui, NB_ui, nchunks_ui, bitmap,
        (const float4*)item_emb, (ushort4*)xb0, n4);
    pass_b<<<NB_ii + NB_ui, TBB, 0, stream>>>(
        tmp_ii, tab_ii, nchunks_ii, edges_ii, rp_ii, rpe_ii, NB_ii,
        tmp_ui, tab_ui, nchunks_ui, edges_ui, rp_ui, rpe_ui);

    // ---- bf16 x0 fallback conversion (only when not fused), 3 layers ----
    if (!fuse_conv)
        conv_bf16<<<(n4 + TB - 1) / TB, TB, 0, stream>>>((const float4*)item_emb, (ushort4*)xb0, n4);
    const int nwaves = (MM + 1) / 2;                      // dual-row waves
    const int ii_blocks = (nwaves * 64 + TB - 1) / TB;
    spmm_bf16<true,  true ><<<ii_blocks, TB, 0, stream>>>(rp_ii, rpe_ii, edges_ii, xb0, y1, xb0, accb, att, 0, MM);
    spmm_bf16<true,  false><<<ii_blocks, TB, 0, stream>>>(rp_ii, rpe_ii, edges_ii, y1,  y2, nullptr, accb, att, 1, MM);
    spmm_bf16<false, false><<<ii_blocks, TB, 0, stream>>>(rp_ii, rpe_ii, edges_ii, y2,  nullptr, nullptr, accb, att, 2, MM);

    // ---- fused user aggregation + pair dot ----
    user_dot_kernel<<<(B * 64 + TB - 1) / TB, TB, 0, stream>>>(users, items, rp_ui, rpe_ui, edges_ui, accb,
                                                               (float*)d_out, B);
}